// Round 1
// baseline (662.197 us; speedup 1.0000x reference)
//
#include <hip/hip_runtime.h>
#include <math.h>

#define D 128
#define CHUNKSZ 64
#define NCHUNK 128
#define LSEQ 8192
#define BASE_LR 0.005f
#define META_LR 0.01f
#define XPAD 130   // floats per LDS row: stride 520B -> 2-way bank aliasing (free), 8B aligned

__global__ __launch_bounds__(512, 2) void lfltm_fwd(
    const float* __restrict__ X,
    const float* __restrict__ init_mem,
    const float* __restrict__ init_opt,
    float* __restrict__ out)
{
    __shared__ float xs[CHUNKSZ * XPAD];   // 33280 B: x chunk, [c][j] padded
    __shared__ float ms[8][D];             //  4096 B: per-wave chunk-start mem row
    __shared__ float es[8][CHUNKSZ];       //  2048 B: per-wave e[c]
    __shared__ float outs[CHUNKSZ][9];     //  2304 B: out staging (pad 9: 2-way only)

    const int tid  = threadIdx.x;
    const int w    = tid >> 6;        // wave 0..7 -> row within group
    const int lane = tid & 63;        // owns j = {2*lane, 2*lane+1}

    // XCD-aware mapping: all 16 blocks of a batch land on (at most) one XCD pair slot
    const int bid  = blockIdx.x;
    const int xcd  = bid & 7;
    const int slot = bid >> 3;        // 0..31
    const int b    = xcd + 8 * (slot & 1);   // batch 0..15
    const int rg   = slot >> 1;       // row group 0..15
    const int i    = rg * 8 + w;      // row 0..127

    const float* __restrict__ Xb = X + (size_t)b * (LSEQ * D);
    float* __restrict__ Ob       = out + (size_t)b * (LSEQ * D);

    // ---- load per-lane state (row i, j-pair) ----
    float m0 = init_mem[i * D + 2 * lane];
    float m1 = init_mem[i * D + 2 * lane + 1];
    float o0 = init_opt[i * D + 2 * lane];
    float o1 = init_opt[i * D + 2 * lane + 1];
    float lr0 = 1.0f / (1.0f + expf(-o0));
    float lr1 = 1.0f / (1.0f + expf(-o1));

    // ---- prefetch chunk 0 into registers ----
    float4 pf0, pf1, pf2, pf3;
    {
        const float4* src = (const float4*)Xb;
        pf0 = src[0 * 512 + tid];
        pf1 = src[1 * 512 + tid];
        pf2 = src[2 * 512 + tid];
        pf3 = src[3 * 512 + tid];
    }

    for (int ch = 0; ch < NCHUNK; ++ch) {
        // ---- stage prefetched x into padded LDS ----
        {
            float4 v[4] = {pf0, pf1, pf2, pf3};
            #pragma unroll
            for (int r = 0; r < 4; ++r) {
                int f = (r * 512 + tid) * 4;     // flat float index in chunk
                int c = f >> 7;                  // token row
                int j = f & (D - 1);
                float* dst = &xs[c * XPAD + j];
                *(float2*)(dst)     = make_float2(v[r].x, v[r].y);
                *(float2*)(dst + 2) = make_float2(v[r].z, v[r].w);
            }
        }
        // stage chunk-start mem row for e-phase
        *(float2*)&ms[w][2 * lane] = make_float2(m0, m1);

        __syncthreads();

        // ---- prefetch next chunk (overlaps compute) ----
        {
            int chn = (ch + 1 < NCHUNK) ? ch + 1 : ch;
            const float4* src = (const float4*)(Xb + (size_t)chn * (CHUNKSZ * D));
            pf0 = src[0 * 512 + tid];
            pf1 = src[1 * 512 + tid];
            pf2 = src[2 * 512 + tid];
            pf3 = src[3 * 512 + tid];
        }

        // ---- e-phase: lane = token c, full dot(mem_row, x[c]) ----
        const float* xrow = &xs[lane * XPAD];
        float acc0 = 0.f, acc1 = 0.f, acc2 = 0.f, acc3 = 0.f;
        #pragma unroll
        for (int jq = 0; jq < D / 4; ++jq) {
            float4 m4  = *(const float4*)&ms[w][jq * 4];      // uniform -> broadcast
            float2 xa  = *(const float2*)&xrow[jq * 4];
            float2 xb2 = *(const float2*)&xrow[jq * 4 + 2];
            acc0 = fmaf(m4.x, xa.x,  acc0);
            acc1 = fmaf(m4.y, xa.y,  acc1);
            acc2 = fmaf(m4.z, xb2.x, acc2);
            acc3 = fmaf(m4.w, xb2.y, acc3);
        }
        float dotv = (acc0 + acc1) + (acc2 + acc3);
        float e = dotv - xrow[i];
        es[w][lane] = e;
        asm volatile("s_waitcnt lgkmcnt(0)" ::: "memory");  // es visible wave-wide

        // ---- sequential token loop (state march) ----
        float S0 = 0.f, S1 = 0.f, Q0 = 0.f, Q1 = 0.f;
        float parr[CHUNKSZ];
        #pragma unroll
        for (int cq = 0; cq < CHUNKSZ / 4; ++cq) {
            float4 e4 = *(const float4*)&es[w][cq * 4];       // uniform broadcast
            #pragma unroll
            for (int u = 0; u < 4; ++u) {
                const int c = cq * 4 + u;
                float ec = (u == 0) ? e4.x : (u == 1) ? e4.y : (u == 2) ? e4.z : e4.w;
                float2 x2 = *(const float2*)&xs[c * XPAD + 2 * lane];
                float ex0 = ec * x2.x;
                float ex1 = ec * x2.y;
                S0 += ex0;
                S1 += ex1;
                float pc = (lr0 * x2.x) * S0;
                pc = fmaf(lr1 * x2.y, S1, pc);
                Q0 = fmaf(ex0, ex0, Q0);
                Q1 = fmaf(ex1, ex1, Q1);
                parr[c] = pc;   // static index (fully unrolled)
            }
        }

        // ---- reduce-scatter parr across 64 lanes: lane l ends with total p[token=l]
        #pragma unroll
        for (int o = 32; o >= 1; o >>= 1) {
            const bool hi = (lane & o) != 0;
            #pragma unroll
            for (int t = 0; t < o; ++t) {
                float send = hi ? parr[t] : parr[t + o];
                float recv = __shfl_xor(send, o, 64);
                parr[t] = (hi ? parr[t + o] : parr[t]) + recv;
            }
        }
        // out[c=lane] = dot - BASE_LR * p_total  (dotv lives in the same lane)
        outs[lane][w] = dotv - BASE_LR * parr[0];

        // ---- chunk-end state update ----
        m0 = fmaf(-BASE_LR * lr0, S0, m0);
        m1 = fmaf(-BASE_LR * lr1, S1, m1);
        o0 = fmaf(-META_LR * lr0 * (1.f - lr0), Q0, o0);
        o1 = fmaf(-META_LR * lr1 * (1.f - lr1), Q1, o1);
        lr0 = 1.0f / (1.0f + expf(-o0));
        lr1 = 1.0f / (1.0f + expf(-o1));

        __syncthreads();

        // ---- write out tile: 512 floats, 8 consecutive i per token (32B segments) ----
        {
            int c  = tid >> 3;
            int ww = tid & 7;
            Ob[(size_t)(ch * CHUNKSZ + c) * D + rg * 8 + ww] = outs[c][ww];
        }
    }
}

extern "C" void kernel_launch(void* const* d_in, const int* in_sizes, int n_in,
                              void* d_out, int out_size, void* d_ws, size_t ws_size,
                              hipStream_t stream) {
    const float* X  = (const float*)d_in[0];
    const float* im = (const float*)d_in[1];
    const float* io = (const float*)d_in[2];
    float* O        = (float*)d_out;
    hipLaunchKernelGGL(lfltm_fwd, dim3(256), dim3(512), 0, stream, X, im, io, O);
}

// Round 2
// 578.642 us; speedup vs baseline: 1.1444x; 1.1444x over previous
//
#include <hip/hip_runtime.h>
#include <math.h>

#define D 128
#define CHK 64
#define NCHUNK 128
#define LSEQ 8192
#define B_LR 0.005f
#define M_LR 0.01f

typedef float f2 __attribute__((ext_vector_type(2)));

// packed fp32 (VOP3P) — hipcc does not reliably emit these from scalar code
__device__ __forceinline__ f2 pk_mul(f2 a, f2 b){ f2 d; asm("v_pk_mul_f32 %0, %1, %2" : "=v"(d) : "v"(a), "v"(b)); return d; }
__device__ __forceinline__ f2 pk_fma(f2 a, f2 b, f2 c){ f2 d; asm("v_pk_fma_f32 %0, %1, %2, %3" : "=v"(d) : "v"(a), "v"(b), "v"(c)); return d; }

template<int C>
__device__ __forceinline__ float dppx(float x){
  return __int_as_float(__builtin_amdgcn_update_dpp(0, __float_as_int(x), C, 0xF, 0xF, true));
}
__device__ __forceinline__ void pl32swap(float &a, float &b){ asm("v_permlane32_swap_b32 %0, %1" : "+v"(a), "+v"(b)); }
__device__ __forceinline__ void pl16swap(float &a, float &b){ asm("v_permlane16_swap_b32 %0, %1" : "+v"(a), "+v"(b)); }

// transpose-reduce: input a[64] per lane; lane L returns sum over all 64 lanes of a[L].
// Identical lane/element mapping as the verified shfl_xor butterfly, but:
//   xor32/xor16 -> permlane swaps (VALU), xor8/2/1 -> DPP (VALU), xor4 -> ds_swizzle (4 DS total)
__device__ __forceinline__ float butterfly64(float* a, int lane){
  #pragma unroll
  for (int t = 0; t < 32; ++t){ float u=a[t], w=a[t+32]; pl32swap(u,w); a[t]=u+w; }
  #pragma unroll
  for (int t = 0; t < 16; ++t){ float u=a[t], w=a[t+16]; pl16swap(u,w); a[t]=u+w; }
  const bool h8 = (lane & 8) != 0, h4 = (lane & 4) != 0, h2 = (lane & 2) != 0, h1 = (lane & 1) != 0;
  #pragma unroll
  for (int t = 0; t < 8; ++t){
    float send = h8 ? a[t] : a[t+8];
    float keep = h8 ? a[t+8] : a[t];
    a[t] = keep + dppx<0x128>(send);                  // row_ror:8 == lane^8
  }
  #pragma unroll
  for (int t = 0; t < 4; ++t){
    float send = h4 ? a[t] : a[t+4];
    float keep = h4 ? a[t+4] : a[t];
    a[t] = keep + __int_as_float(__builtin_amdgcn_ds_swizzle(__float_as_int(send), 0x101F)); // lane^4
  }
  #pragma unroll
  for (int t = 0; t < 2; ++t){
    float send = h2 ? a[t] : a[t+2];
    float keep = h2 ? a[t+2] : a[t];
    a[t] = keep + dppx<0x4E>(send);                   // quad_perm xor2
  }
  float send = h1 ? a[0] : a[1];
  float keep = h1 ? a[1] : a[0];
  return keep + dppx<0xB1>(send);                     // quad_perm xor1
}

__device__ __forceinline__ void gl_lds16(const float* g, float* l){
  __builtin_amdgcn_global_load_lds((const __attribute__((address_space(1))) float*)g,
                                   (__attribute__((address_space(3))) float*)l, 16, 0, 0);
}

__global__ __launch_bounds__(512, 1) void lfltm_fwd(
    const float* __restrict__ X,
    const float* __restrict__ init_mem,
    const float* __restrict__ init_opt,
    float* __restrict__ out)
{
  __shared__ float xs[2][CHK * D];       // 64 KiB: double-buffered x chunk, linear [c][j]
  __shared__ float es[8][CHK];           // per-wave e broadcast (wave-private, no barrier)
  __shared__ float outs[2][CHK * 9];     // out staging, pad 9 (2-way bank alias only)

  const int tid  = threadIdx.x;
  const int w    = tid >> 6;             // wave -> row within group
  const int lane = tid & 63;             // owns j = {2*lane, 2*lane+1}

  // XCD-aware: all blocks of one batch on one XCD (L2 reuse of X)
  const int bid  = blockIdx.x;
  const int xcd  = bid & 7;
  const int slot = bid >> 3;
  const int b    = xcd + 8 * (slot & 1);
  const int rg   = slot >> 1;
  const int i    = rg * 8 + w;

  const float* __restrict__ Xb = X + (size_t)b * (LSEQ * D);
  float* __restrict__ Ob       = out + (size_t)b * (LSEQ * D);

  // per-lane state: mem row pair + opt pair
  float m0 = init_mem[i * D + 2*lane];
  float m1 = init_mem[i * D + 2*lane + 1];
  float o0 = init_opt[i * D + 2*lane];
  float o1 = init_opt[i * D + 2*lane + 1];
  const float u0 = (2*lane     == i) ? 1.0f : 0.0f;   // delta_i fold: e = (m - e_i).x
  const float u1 = (2*lane + 1 == i) ? 1.0f : 0.0f;

  // prologue: chunk 0 -> buf 0 (async direct-to-LDS)
  #pragma unroll
  for (int r = 0; r < 4; ++r)
    gl_lds16(Xb + (r*512 + tid)*4, &xs[0][(r*512 + tid)*4]);
  __syncthreads();                       // drains vmcnt before barrier

  for (int ch = 0; ch < NCHUNK; ++ch) {
    const int cur = ch & 1;

    // (a) coalesced store of previous chunk's outputs (after last barrier)
    if (ch > 0) {
      const int c = tid >> 3, ww = tid & 7;
      Ob[(size_t)((ch-1)*CHK + c)*D + rg*8 + ww] = outs[cur ^ 1][c*9 + ww];
    }

    // (b) prefetch next chunk -> other buffer (in flight across whole compute)
    {
      int chn = ch + 1; if (chn >= NCHUNK) chn = NCHUNK - 1;   // last iter: harmless dup
      const float* gb = Xb + (size_t)chn * (CHK * D);
      #pragma unroll
      for (int r = 0; r < 4; ++r)
        gl_lds16(gb + (r*512 + tid)*4, &xs[cur ^ 1][(r*512 + tid)*4]);
    }

    // (c) x[token=lane, i] gather from global (VMEM pipe is idle; L2-hot)
    const float xci = Xb[(size_t)(ch*CHK + lane)*D + i];

    const float lr0 = 1.0f / (1.0f + __expf(-o0));
    const float lr1 = 1.0f / (1.0f + __expf(-o1));
    f2 lr2; lr2.x = lr0; lr2.y = lr1;
    f2 mp;  mp.x = m0 - u0; mp.y = m1 - u1;

    // (d) pass 1: read own column-pair once (conflict-free contiguous b64),
    //     partial dots -> butterfly => lane c holds e_c
    f2 xr[CHK];
    float arr[CHK];
    const float* xb = &xs[cur][2*lane];
    #pragma unroll
    for (int c = 0; c < CHK; ++c){
      xr[c] = *(const f2*)(xb + c*D);
      f2 t = pk_mul(mp, xr[c]);
      arr[c] = t.x + t.y;
    }
    const float e_own = butterfly64(arr, lane);
    es[w][lane] = e_own;                 // wave-private broadcast buffer

    // (e) sequential token march, x in registers, lr fused into prefix (S' = lr*S)
    f2 Sp; Sp.x = 0.f; Sp.y = 0.f;
    f2 Q2; Q2.x = 0.f; Q2.y = 0.f;
    #pragma unroll
    for (int cg = 0; cg < CHK/4; ++cg){
      float4 e4 = *(const float4*)&es[w][cg*4];      // uniform -> LDS broadcast
      #pragma unroll
      for (int u = 0; u < 4; ++u){
        const int c = cg*4 + u;
        const float ec = (u==0)?e4.x:(u==1)?e4.y:(u==2)?e4.z:e4.w;
        f2 e2; e2.x = ec; e2.y = ec;
        f2 ex  = pk_mul(e2, xr[c]);                  // e_c * x
        Sp     = pk_fma(lr2, ex, Sp);                // S' += lr * e * x
        f2 pc2 = pk_mul(xr[c], Sp);                  // x * S' (post-update: inclusive)
        Q2     = pk_fma(ex, ex, Q2);                 // Q += (e x)^2
        arr[c] = pc2.x + pc2.y;
      }
    }
    const float p = butterfly64(arr, lane);          // lane c: p_c = sum_j lr_j x_cj S_cj

    // (f) out = dot(mem, x_c) - B_LR*p = e_c + x_ci - B_LR*p
    outs[cur][lane*9 + w] = e_own + xci - B_LR * p;

    // (g) chunk-end state update (mem uses S' directly: mem -= B_LR * lr * S)
    m0 = fmaf(-B_LR, Sp.x, m0);
    m1 = fmaf(-B_LR, Sp.y, m1);
    o0 = fmaf(-M_LR * lr0 * (1.f - lr0), Q2.x, o0);
    o1 = fmaf(-M_LR * lr1 * (1.f - lr1), Q2.y, o1);

    // (h) single barrier: drains glds (next chunk ready), publishes outs
    __syncthreads();
  }

  // epilogue: final chunk's outputs
  {
    const int c = tid >> 3, ww = tid & 7;
    Ob[(size_t)((NCHUNK-1)*CHK + c)*D + rg*8 + ww] = outs[(NCHUNK-1)&1][c*9 + ww];
  }
}

extern "C" void kernel_launch(void* const* d_in, const int* in_sizes, int n_in,
                              void* d_out, int out_size, void* d_ws, size_t ws_size,
                              hipStream_t stream) {
    const float* X  = (const float*)d_in[0];
    const float* im = (const float*)d_in[1];
    const float* io = (const float*)d_in[2];
    float* O        = (float*)d_out;
    hipLaunchKernelGGL(lfltm_fwd, dim3(256), dim3(512), 0, stream, X, im, io, O);
}